// Round 1
// baseline (454260.107 us; speedup 1.0000x reference)
//
#include <hip/hip_runtime.h>
#include <math.h>

// HierarchicalRecursiveTRM on MI355X.
// 8 teams (one per XCD via blockIdx%8), 2 batches per team, 32 WGs per team.
// Each WG holds a 1/32 row-slice of ALL weights in LDS (f32, ~139KB).
// Per time step: 13 sliced mat-vec stages, each followed by a team barrier
// (monotonic counter in d_ws, agent-scope release/acquire) and a replicated
// elementwise update. Dead zL computations (L-iters 1,2,4,5) are skipped.

#define NB   16
#define SEQ  4096
#define TEAMS 8
#define WPT  32      // workgroups per team
#define BPT  2       // batches per team
#define NTH  256     // threads per workgroup

__device__ __forceinline__ float sigf(float v){ return 1.0f/(1.0f+expf(-v)); }

extern "C" __global__ __launch_bounds__(NTH, 1)
void trm_kernel(const float* __restrict__ x,   const float* __restrict__ h0,
                const float* __restrict__ wih, const float* __restrict__ whh,
                const float* __restrict__ bih, const float* __restrict__ bhh,
                const float* __restrict__ Lgw, const float* __restrict__ Lgb,
                const float* __restrict__ Ltw, const float* __restrict__ Ltb,
                const float* __restrict__ Luw, const float* __restrict__ Lub,
                const float* __restrict__ Hgw, const float* __restrict__ Hgb,
                const float* __restrict__ Htw, const float* __restrict__ Htb,
                const float* __restrict__ Huw, const float* __restrict__ Hub,
                float* __restrict__ out,
                unsigned* __restrict__ cnt_base, float* __restrict__ act_base)
{
  const int team = blockIdx.x & (TEAMS-1);   // XCD-local team (heuristic; correctness-independent)
  const int j    = blockIdx.x / TEAMS;       // 0..31 slice id within team
  const int tid  = threadIdx.x;

  // ---- LDS: weight slices (row stride +1 to spread banks) + replicated state ----
  __shared__ float wgA[16][513];  // GRU r,z rows: [x(256) | h(256)]
  __shared__ float wgX[8][257];   // GRU n-gate, x part (w_ih rows 512..767)
  __shared__ float wgN[8][257];   // GRU n-gate, h part (w_hh rows 512..767)
  __shared__ float wcl[16][513];  // [Lg_w ; Lt_w] stacked rows
  __shared__ float wch[16][513];  // [Hg_w ; Ht_w] stacked rows
  __shared__ float wul[8][257];   // Lu_w rows
  __shared__ float wuh[8][257];   // Hu_w rows
  __shared__ float xst[BPT][256];
  __shared__ float st_o [BPT][256];
  __shared__ float st_zh[BPT][256];
  __shared__ float st_zl[BPT][256];
  __shared__ float st_h [BPT][256];
  __shared__ float bRZ[16], bX[8], bN[8], bCL[16], bCH[16], bUL[8], bUH[8];

  // ---------- one-time weight staging into LDS ----------
  {
    const int k = tid; // 0..255
    for (int r=0;r<16;r++){
      const int n = j*16+r;                 // 0..511
      wgA[r][k]     = wih[n*256+k];
      wgA[r][256+k] = whh[n*256+k];
      const float* sl = (n<256)? (Lgw + n*512) : (Ltw + (size_t)(n-256)*512);
      const float* sh = (n<256)? (Hgw + n*512) : (Htw + (size_t)(n-256)*512);
      wcl[r][k] = sl[k]; wcl[r][256+k] = sl[256+k];
      wch[r][k] = sh[k]; wch[r][256+k] = sh[256+k];
    }
    for (int r=0;r<8;r++){
      const int n = 512 + j*8 + r;
      wgX[r][k] = wih[n*256+k];
      wgN[r][k] = whh[n*256+k];
      const int u = j*8+r;
      wul[r][k] = Luw[u*256+k];
      wuh[r][k] = Huw[u*256+k];
    }
    if (tid<16){
      const int n = j*16+tid;
      bRZ[tid] = bih[n] + bhh[n];
      bCL[tid] = (n<256)? Lgb[n] : Ltb[n-256];
      bCH[tid] = (n<256)? Hgb[n] : Htb[n-256];
    }
    if (tid<8){
      bX[tid]  = bih[512 + j*8 + tid];
      bN[tid]  = bhh[512 + j*8 + tid];
      bUL[tid] = Lub[j*8+tid];
      bUH[tid] = Hub[j*8+tid];
    }
    for (int u=tid; u<BPT*256; u+=NTH){
      const int b=u>>8, i=u&255;
      st_h[b][i]  = h0[(team*BPT+b)*256+i];
      st_o[b][i]  = 0.f;
      st_zh[b][i] = 0.f;
      st_zl[b][i] = 0.f;
    }
  }
  __syncthreads();

  unsigned* cnt  = cnt_base + team*64;                       // 256B-separated counters
  float*    actT = act_base + (size_t)team*(2*BPT*1024);     // 2 alternating buffers
  unsigned  kst  = 0;                                        // global stage index

  auto barrier = [&](){
    __syncthreads();  // all waves' global slice-stores drained (vmcnt before s_barrier)
    if (tid==0){
      __hip_atomic_fetch_add(cnt, 1u, __ATOMIC_RELEASE, __HIP_MEMORY_SCOPE_AGENT);
      const unsigned tgt = (kst+1u)*WPT;
      while (__hip_atomic_load(cnt, __ATOMIC_ACQUIRE, __HIP_MEMORY_SCOPE_AGENT) < tgt)
        __builtin_amdgcn_s_sleep(1);
    }
    __syncthreads();
    kst++;
  };

  // C-cell stage: 16 rows/WG, K=512 = [o | hid]; then replicated gate update of o.
  auto cstage = [&](float (*W)[513], float* bC, float (*hid)[256], bool wout, int tt){
    __syncthreads();
    float* buf = actT + (kst&1u)*(BPT*1024);
    const int r = tid>>4, kk = tid&15;
    const float* wr = W[r];
    float a0=0.f, a1=0.f;
    #pragma unroll
    for (int i=0;i<16;i++){
      const float w = wr[kk+16*i];
      a0 += w*st_o[0][kk+16*i];
      a1 += w*st_o[1][kk+16*i];
    }
    #pragma unroll
    for (int i=0;i<16;i++){
      const float w = wr[256+kk+16*i];
      a0 += w*hid[0][kk+16*i];
      a1 += w*hid[1][kk+16*i];
    }
    a0 += __shfl_xor(a0,1); a0 += __shfl_xor(a0,2); a0 += __shfl_xor(a0,4); a0 += __shfl_xor(a0,8);
    a1 += __shfl_xor(a1,1); a1 += __shfl_xor(a1,2); a1 += __shfl_xor(a1,4); a1 += __shfl_xor(a1,8);
    if (kk==0){
      const int n = j*16+r;
      buf[n]      = a0 + bC[r];
      buf[1024+n] = a1 + bC[r];
    }
    barrier();
    for (int u=tid; u<BPT*256; u+=NTH){
      const int b=u>>8, i=u&255;
      const float g  = sigf(buf[b*1024+i]);
      const float rr = tanhf(buf[b*1024+256+i]);
      const float o  = g*rr + (1.f-g)*st_o[b][i];
      st_o[b][i] = o;
      if (wout) out[((size_t)(team*BPT+b)*SEQ + tt)*256 + i] = o;
    }
  };

  // U-cell stage: 8 rows/WG, K=256 over st_o; dst = tanh(pre).
  auto ustage = [&](float (*W)[257], float* bU, float (*dst)[256]){
    __syncthreads();
    float* buf = actT + (kst&1u)*(BPT*1024);
    const int r = tid>>5, kk = tid&31;
    const float* wr = W[r];
    float a0=0.f, a1=0.f;
    #pragma unroll
    for (int i=0;i<8;i++){
      const float w = wr[kk+32*i];
      a0 += w*st_o[0][kk+32*i];
      a1 += w*st_o[1][kk+32*i];
    }
    a0 += __shfl_xor(a0,1); a0 += __shfl_xor(a0,2); a0 += __shfl_xor(a0,4); a0 += __shfl_xor(a0,8); a0 += __shfl_xor(a0,16);
    a1 += __shfl_xor(a1,1); a1 += __shfl_xor(a1,2); a1 += __shfl_xor(a1,4); a1 += __shfl_xor(a1,8); a1 += __shfl_xor(a1,16);
    if (kk==0){
      const int n = j*8+r;
      buf[n]      = a0 + bU[r];
      buf[1024+n] = a1 + bU[r];
    }
    barrier();
    for (int u=tid; u<BPT*256; u+=NTH){
      const int b=u>>8, i=u&255;
      dst[b][i] = tanhf(buf[b*1024+i]);
    }
  };

  #pragma unroll 1
  for (int t=0; t<SEQ; ++t){
    // ---- stage 0: GRU (r,z combined; xn & hn separate for the r*hn term) ----
    __syncthreads();
    for (int u=tid; u<BPT*256; u+=NTH){
      const int b=u>>8, i=u&255;
      xst[b][i] = x[((size_t)(team*BPT+b)*SEQ + t)*256 + i];
    }
    __syncthreads();
    {
      float* buf = actT + (kst&1u)*(BPT*1024);
      const int r = tid>>4, kk = tid&15;
      { // r,z rows: K=512 = [x | h], bias = b_ih + b_hh
        const float* wr = wgA[r];
        float a0=0.f, a1=0.f;
        #pragma unroll
        for (int i=0;i<16;i++){
          const float w = wr[kk+16*i];
          a0 += w*xst[0][kk+16*i];
          a1 += w*xst[1][kk+16*i];
        }
        #pragma unroll
        for (int i=0;i<16;i++){
          const float w = wr[256+kk+16*i];
          a0 += w*st_h[0][kk+16*i];
          a1 += w*st_h[1][kk+16*i];
        }
        a0 += __shfl_xor(a0,1); a0 += __shfl_xor(a0,2); a0 += __shfl_xor(a0,4); a0 += __shfl_xor(a0,8);
        a1 += __shfl_xor(a1,1); a1 += __shfl_xor(a1,2); a1 += __shfl_xor(a1,4); a1 += __shfl_xor(a1,8);
        if (kk==0){
          const int n=j*16+r;
          buf[n]      = a0 + bRZ[r];
          buf[1024+n] = a1 + bRZ[r];
        }
      }
      { // n-gate short rows: sr<8 -> xn (K=x), sr>=8 -> hn (K=h)
        const int sr = tid>>4;
        const float* wr = (sr<8)? wgX[sr] : wgN[sr-8];
        float (*src)[256] = (sr<8)? xst : st_h;
        float a0=0.f, a1=0.f;
        #pragma unroll
        for (int i=0;i<16;i++){
          const float w = wr[kk+16*i];
          a0 += w*src[0][kk+16*i];
          a1 += w*src[1][kk+16*i];
        }
        a0 += __shfl_xor(a0,1); a0 += __shfl_xor(a0,2); a0 += __shfl_xor(a0,4); a0 += __shfl_xor(a0,8);
        a1 += __shfl_xor(a1,1); a1 += __shfl_xor(a1,2); a1 += __shfl_xor(a1,4); a1 += __shfl_xor(a1,8);
        if (kk==0){
          const int nn = (sr<8)? (512 + j*8 + sr) : (768 + j*8 + (sr-8));
          const float bb = (sr<8)? bX[sr] : bN[sr-8];
          buf[nn]      = a0 + bb;
          buf[1024+nn] = a1 + bb;
        }
      }
      barrier();
      const bool last = (t==SEQ-1);
      for (int u=tid; u<BPT*256; u+=NTH){
        const int b=u>>8, i=u&255;
        const float pr = buf[b*1024 + i];
        const float pz = buf[b*1024 + 256 + i];
        const float xn = buf[b*1024 + 512 + i];
        const float hn = buf[b*1024 + 768 + i];
        const float rg = sigf(pr);
        const float zg = sigf(pz);
        const float ng = tanhf(xn + rg*hn);
        const float hv = (1.f-zg)*ng + zg*st_h[b][i];
        st_h[b][i] = hv;
        st_o[b][i] = hv;
        if (last) out[(size_t)NB*SEQ*256 + (team*BPT+b)*256 + i] = hv;
      }
    }
    // ---- refinement: 2 H-cycles of (3x L-cell, U_L, H-cell, U_H) ----
    #pragma unroll 1
    for (int c=0;c<2;c++){
      cstage(wcl,bCL,st_zh,false,t);
      cstage(wcl,bCL,st_zh,false,t);
      cstage(wcl,bCL,st_zh,false,t);
      ustage(wul,bUL,st_zl);
      cstage(wch,bCH,st_zl,(c==1),t);   // second H-cell output = refined[t]
      ustage(wuh,bUH,st_zh);
    }
  }
}

extern "C" void kernel_launch(void* const* d_in, const int* in_sizes, int n_in,
                              void* d_out, int out_size, void* d_ws, size_t ws_size,
                              hipStream_t stream)
{
  // ws layout: [0,4096): team counters (256B apart). [4096, +128KB): activation buffers.
  hipMemsetAsync(d_ws, 0, 4096, stream);
  unsigned* cnt = (unsigned*)d_ws;
  float*    act = (float*)((char*)d_ws + 4096);

  dim3 grid(TEAMS*WPT), block(NTH);
  hipLaunchKernelGGL(trm_kernel, grid, block, 0, stream,
    (const float*)d_in[0],  (const float*)d_in[1],
    (const float*)d_in[2],  (const float*)d_in[3],
    (const float*)d_in[4],  (const float*)d_in[5],
    (const float*)d_in[6],  (const float*)d_in[7],
    (const float*)d_in[8],  (const float*)d_in[9],
    (const float*)d_in[10], (const float*)d_in[11],
    (const float*)d_in[12], (const float*)d_in[13],
    (const float*)d_in[14], (const float*)d_in[15],
    (const float*)d_in[16], (const float*)d_in[17],
    (float*)d_out, cnt, act);
}